// Round 5
// baseline (592.484 us; speedup 1.0000x reference)
//
#include <hip/hip_runtime.h>

// RichAttentionLayer: B=2048, S=200, D=192, H1=64, H2=32, IN=768.
// One block per batch b. Layer-1 decomposed:
//   x@W1 = k @ M_b + c_b,  M_b[d,h] = W1a[d,h] + W1d[d,h] + q[d]*W1c[d,h]
//   c_b[h] = b1[h] + sum_d q[d]*(W1b[d,h] - W1d[d,h])
// 64-row S-tiles. GEMM1 h-split across waves; GEMM2/layer3/softmax/o-accum
// fully per-wave -> 3 barriers per tile, no wave-serial sections.
//
// R1: LDS diet 46.9K -> 38.8K (unions).
// R3/R4: register-pressure surgery -> NO counter movement (VGPR pinned 64,
//     WRITE_SIZE ~220MB regardless). Spill theory dead.
// R5: measured model: 490MB HBM / 220us = 2.3TB/s = measured hbm_gbps ->
//     kernel is BW-bound at 35% of achievable because loads only issue
//     during staging (~30% duty cycle). Fix: T14 register prefetch —
//     issue tile t+1's 12 float4 right after tile t's staging barrier
//     (in flight during GEMM1/2/softmax/o-accum); cvt+write at next loop
//     top. Tile 0 issued at kernel entry (hides under phase A/B).
//     48 held VGPRs -> __launch_bounds__(256,3) (170-reg budget).

#define B_N 2048
#define S_N 200
#define D_N 192

typedef __bf16 bf16x8 __attribute__((ext_vector_type(8)));
typedef __bf16 bf16x4 __attribute__((ext_vector_type(4)));
typedef float  f32x4  __attribute__((ext_vector_type(4)));

__device__ __forceinline__ float rfl(float x) {
  return __uint_as_float(__builtin_amdgcn_readfirstlane(__float_as_uint(x)));
}

struct __align__(16) Smem {
  unsigned char kbuf[64*400];     // bf16[64][200] (192 used), row stride 400 B
  union {                         // w2t consumed into regs before phase-B
    unsigned char h1buf[64*144];  // barrier; h1buf first written after it.
    unsigned char w2t[32*144];    // bf16 w2t[k2][h] = W2[h][k2]
  };
  union {                         // qbuf dead after phase-B barrier; scores
    float qbuf[192];              // first written tile 0 post-staging-barrier.
    float scores[256];
  };
  float cbuf[64];
  union {                         // cpart dead after cbuf computed (pre tile
    float cpart[4][64];           // 0); opart first written after final tile
    float opart[4][192];          // barrier.
  };
  unsigned char maskbuf[256];
  float wm[4], wl[4];             // per-wave softmax state
  float w3buf[32];
  float b2buf[32];
  float consts[4];                // a1, a2, b3
};

__global__ __launch_bounds__(256, 3) void rich_attn_kernel(
    const float* __restrict__ query, const float* __restrict__ keys,
    const int*   __restrict__ keys_mask, const float* __restrict__ W1,
    const float* __restrict__ b1, const float* __restrict__ a1,
    const float* __restrict__ W2, const float* __restrict__ b2,
    const float* __restrict__ a2, const float* __restrict__ W3,
    const float* __restrict__ b3, float* __restrict__ out)
{
  __shared__ Smem sm;
  const int tid  = threadIdx.x;
  const int b    = blockIdx.x;
  const int wave = tid >> 6;
  const int lane = tid & 63;
  const int quad = (tid >> 4) & 3;
  const int n16  = tid & 15;

  const float* kb = keys + (size_t)b * (S_N * D_N);

  // ---- prefetch registers: 12 float4 = one 64-row keys tile ----
  float4 v[12];
  auto issue_tile = [&](int s0_) {
    #pragma unroll
    for (int u = 0; u < 12; ++u) {
      int f = tid + u*256;                        // 0..3071
      int sg = s0_ + f/48;
      v[u] = make_float4(0.f, 0.f, 0.f, 0.f);
      if (sg < 200) v[u] = ((const float4*)kb)[sg*48 + (f%48)];
    }
  };
  auto write_tile = [&]() {
    #pragma unroll
    for (int u = 0; u < 12; ++u) {
      int f = tid + u*256;
      int row = f/48, c4 = f%48;
      bf16x4 bv;
      bv[0]=(__bf16)v[u].x; bv[1]=(__bf16)v[u].y;
      bv[2]=(__bf16)v[u].z; bv[3]=(__bf16)v[u].w;
      *(bf16x4*)&sm.kbuf[row*400 + c4*8] = bv;
    }
  };

  issue_tile(0);                                  // tile 0 flies under phase A/B

  // ---- phase A: preload q, mask, scalars, W2^T(bf16), W3 ----
  if (tid < 192) sm.qbuf[tid] = query[b*D_N + tid];
  sm.maskbuf[tid] = (tid < 200) ? (unsigned char)(keys_mask[b*S_N + tid] != 0) : 0;
  if (tid < 32)  sm.w3buf[tid] = W3[tid];
  else if (tid < 64) sm.b2buf[tid-32] = b2[tid-32];
  if (tid == 64) { sm.consts[0] = a1[0]; sm.consts[1] = a2[0]; sm.consts[2] = b3[0]; }
  for (int i = tid; i < 64*32; i += 256) {
    int hh = i >> 5, kk = i & 31;                 // W2[h][k2] row-major
    *((__bf16*)&sm.w2t[kk*144 + hh*2]) = (__bf16)W2[i];
  }
  __syncthreads();

  // ---- phase B: c_b partials; per-wave fb1 (M_b cols, registers); fw2 ----
  {
    int hh = tid & 63, pp = tid >> 6;
    float acc = 0.f;
    int d0 = pp*48;
    #pragma unroll 4
    for (int d = d0; d < d0+48; ++d)
      acc += sm.qbuf[d] * (W1[(192+d)*64 + hh] - W1[(576+d)*64 + hh]);
    sm.cpart[pp][hh] = acc;
  }
  bf16x8 fb1[6];                                  // B-frag: M_b[k=t*32+quad*8+j][n=h]
  {
    int h = (wave << 4) | n16;
    #pragma unroll
    for (int t = 0; t < 6; ++t) {
      #pragma unroll
      for (int j = 0; j < 8; ++j) {
        int d = t*32 + quad*8 + j;
        float v1 = W1[d*64 + h] + W1[(576+d)*64 + h] + sm.qbuf[d]*W1[(384+d)*64 + h];
        fb1[t][j] = (__bf16)v1;
      }
      __builtin_amdgcn_sched_barrier(0);          // cap in-flight W1 loads/t-group
    }
  }
  bf16x8 fw2[2][2];                               // B-frags for GEMM2, both n-tiles
  #pragma unroll
  for (int nt2 = 0; nt2 < 2; ++nt2)
    #pragma unroll
    for (int t = 0; t < 2; ++t)
      fw2[nt2][t] = *(const bf16x8*)&sm.w2t[(nt2*16 + n16)*144 + (t*32 + quad*8)*2];
  // PER-LANE (n16-indexed) -> must stay in VGPRs
  const float w3v0 = sm.w3buf[n16],      w3v1 = sm.w3buf[16 + n16];
  const float bbv0 = sm.b2buf[n16],      bbv1 = sm.b2buf[16 + n16];
  // true scalars -> SGPRs
  const float a1v = rfl(sm.consts[0]), a2v = rfl(sm.consts[1]), b3v = rfl(sm.consts[2]);
  __syncthreads();
  if (tid < 64)
    sm.cbuf[tid] = b1[tid] + sm.cpart[0][tid] + sm.cpart[1][tid]
                 + sm.cpart[2][tid] + sm.cpart[3][tid];
  // cbuf first read after tile-0 staging barrier below.

  float m_run = -1e30f, l_run = 0.f;
  f32x4 o = {0.f, 0.f, 0.f, 0.f};                 // lanes 0..47 own d = lane*4..+3 (per wave)

  for (int tile = 0; tile < 4; ++tile) {
    const int s0 = tile * 64;
    // ---- commit prefetched regs -> LDS (cvt f32->bf16) ----
    write_tile();
    __syncthreads();
    // ---- issue next tile's loads; they fly during compute below ----
    if (tile < 3) issue_tile(s0 + 64);

    // ---- GEMM1: h1_pre[64 x 64]; wave owns h-cols [16w,16w+16) ----
    // one mt-tile at a time (4 AGPR acc, <=6 fa ds_reads in flight).
    {
      int h = (wave << 4) | n16;
      float cb = sm.cbuf[h];
      #pragma unroll
      for (int mt = 0; mt < 4; ++mt) {
        f32x4 acc1 = (f32x4){0.f,0.f,0.f,0.f};
        #pragma unroll
        for (int t = 0; t < 6; ++t) {
          bf16x8 fa = *(const bf16x8*)&sm.kbuf[(mt*16 + n16)*400 + (t*32 + quad*8)*2];
          acc1 = __builtin_amdgcn_mfma_f32_16x16x32_bf16(fa, fb1[t], acc1, 0, 0, 0);
        }
        #pragma unroll
        for (int r = 0; r < 4; ++r) {
          int m = mt*16 + quad*4 + r;             // C layout: row=quad*4+r, col=n16
          float v1 = acc1[r] + cb;
          v1 = (v1 >= 0.f) ? v1 : a1v * v1;
          *((__bf16*)&sm.h1buf[m*144 + h*2]) = (__bf16)v1;
        }
      }
    }
    __syncthreads();

    // ---- per-wave from here: rows 16*wave .. 16*wave+15 of this tile ----
    // GEMM2: h2_pre[16 x 32]
    bf16x8 fa2[2];
    #pragma unroll
    for (int t = 0; t < 2; ++t)
      fa2[t] = *(const bf16x8*)&sm.h1buf[(wave*16 + n16)*144 + (t*32 + quad*8)*2];
    f32x4 acc2[2];
    acc2[0] = (f32x4){0.f,0.f,0.f,0.f};
    acc2[1] = (f32x4){0.f,0.f,0.f,0.f};
    #pragma unroll
    for (int nt2 = 0; nt2 < 2; ++nt2)
      #pragma unroll
      for (int t = 0; t < 2; ++t)
        acc2[nt2] = __builtin_amdgcn_mfma_f32_16x16x32_bf16(fa2[t], fw2[nt2][t], acc2[nt2], 0, 0, 0);

    // layer 3 in-register: sc[r] for row (quad*4+r), butterfly-reduce over n16
    float sc[4];
    #pragma unroll
    for (int r = 0; r < 4; ++r) {
      float v0 = acc2[0][r] + bbv0; v0 = (v0 >= 0.f) ? v0 : a2v * v0;
      float v1 = acc2[1][r] + bbv1; v1 = (v1 >= 0.f) ? v1 : a2v * v1;
      sc[r] = v0 * w3v0 + v1 * w3v1;
    }
    #pragma unroll
    for (int off = 1; off < 16; off <<= 1)
      #pragma unroll
      for (int r = 0; r < 4; ++r) sc[r] += __shfl_xor(sc[r], off);

    // mask + per-wave online softmax (wave-local, no barrier)
    float p[4];
    float mloc = -1e30f;
    #pragma unroll
    for (int r = 0; r < 4; ++r) {
      int sg = s0 + wave*16 + quad*4 + r;
      sc[r] += b3v;
      bool valid = (sg < 200) && (sm.maskbuf[sg] != 0);
      sc[r] = valid ? sc[r] : -1e30f;
      mloc = fmaxf(mloc, sc[r]);
    }
    if (n16 == 0) {
      #pragma unroll
      for (int r = 0; r < 4; ++r) sm.scores[s0 + wave*16 + quad*4 + r] = sc[r];
    }
    mloc = fmaxf(mloc, __shfl_xor(mloc, 16));
    mloc = fmaxf(mloc, __shfl_xor(mloc, 32));
    float m_new = fmaxf(m_run, mloc);
    float fac = __expf(m_run - m_new);
    float psum = 0.f;
    #pragma unroll
    for (int r = 0; r < 4; ++r) {
      p[r] = (sc[r] > -1e29f) ? __expf(sc[r] - m_new) : 0.f;
      psum += p[r];
    }
    psum += __shfl_xor(psum, 16);
    psum += __shfl_xor(psum, 32);
    l_run = l_run * fac + psum;
    m_run = m_new;

    // o += p * keys over wave's 16 rows; p broadcast inline (short liveness)
    o[0] *= fac; o[1] *= fac; o[2] *= fac; o[3] *= fac;
    #pragma unroll
    for (int s2 = 0; s2 < 16; ++s2) {
      float pvs = __shfl(p[s2 & 3], (s2 >> 2) * 16);   // all lanes active
      if (lane < 48) {
        bf16x4 kv = *(const bf16x4*)&sm.kbuf[(wave*16 + s2)*400 + lane*8];
        o[0] += pvs * (float)kv[0];
        o[1] += pvs * (float)kv[1];
        o[2] += pvs * (float)kv[2];
        o[3] += pvs * (float)kv[3];
      }
    }
    __syncthreads();   // kbuf/h1buf reuse next tile (write_tile at loop top)
  }

  // ---- combine 4 per-wave states, finalize ----
  if (lane == 0) { sm.wm[wave] = m_run; sm.wl[wave] = l_run; }
  if (lane < 48) *(f32x4*)&sm.opart[wave][lane*4] = o;
  __syncthreads();
  float mg = fmaxf(fmaxf(sm.wm[0], sm.wm[1]), fmaxf(sm.wm[2], sm.wm[3]));
  float e0 = __expf(sm.wm[0] - mg), e1 = __expf(sm.wm[1] - mg);
  float e2 = __expf(sm.wm[2] - mg), e3 = __expf(sm.wm[3] - mg);
  float lg = sm.wl[0]*e0 + sm.wl[1]*e1 + sm.wl[2]*e2 + sm.wl[3]*e3;
  float invl = (lg > 0.f) ? 1.f / lg : 0.f;
  if (tid < 192) {
    float os = sm.opart[0][tid]*e0 + sm.opart[1][tid]*e1
             + sm.opart[2][tid]*e2 + sm.opart[3][tid]*e3;
    out[(size_t)b * D_N + tid] = os * invl;
  }
  if (tid < 200) {
    float wv = (lg > 0.f) ? __expf(sm.scores[tid] - mg) * invl : 0.f;
    out[(size_t)B_N * D_N + (size_t)b * S_N + tid] = wv;
  }
}

extern "C" void kernel_launch(void* const* d_in, const int* in_sizes, int n_in,
                              void* d_out, int out_size, void* d_ws, size_t ws_size,
                              hipStream_t stream) {
  const float* query     = (const float*)d_in[0];
  const float* keys      = (const float*)d_in[1];
  const int*   keys_mask = (const int*)  d_in[2];
  const float* W1        = (const float*)d_in[3];
  const float* b1        = (const float*)d_in[4];
  const float* a1        = (const float*)d_in[5];
  const float* W2        = (const float*)d_in[6];
  const float* b2        = (const float*)d_in[7];
  const float* a2        = (const float*)d_in[8];
  const float* W3        = (const float*)d_in[9];
  const float* b3        = (const float*)d_in[10];
  float* out = (float*)d_out;
  rich_attn_kernel<<<dim3(B_N), dim3(256), 0, stream>>>(
      query, keys, keys_mask, W1, b1, a1, W2, b2, a2, W3, b3, out);
}

// Round 6
// 505.658 us; speedup vs baseline: 1.1717x; 1.1717x over previous
//
#include <hip/hip_runtime.h>

// RichAttentionLayer: B=2048, S=200, D=192, H1=64, H2=32, IN=768.
// One block per batch b. Layer-1 decomposed:
//   x@W1 = k @ M_b + c_b,  M_b[d,h] = W1a[d,h] + W1d[d,h] + q[d]*W1c[d,h]
//   c_b[h] = b1[h] + sum_d q[d]*(W1b[d,h] - W1d[d,h])
//
// R6 REDESIGN: barrier-free per-wave tiles. Wave w owns rows [64w, 64w+64)
// end-to-end: GEMM1 A-frags f32->bf16 direct from global (kbuf deleted),
// B = Mt[h][d] (M_b transposed) in LDS (block-shared, written phase B),
// h1 in per-wave private LDS chunk (same-wave ds order, no barrier),
// GEMM2/layer3/softmax per 16-row chunk, o-accum re-reads keys from
// global (L2/L3 hit). Main loop: ZERO barriers (4 total, was 14).
// Rationale (R1-R5 counters): lockstep tile phases gave ~30% load duty
// cycle (2.3 of 6.3 TB/s) and pinned allocator at 64 arch VGPRs with
// ~210MB scratch writes; R5 showed held prefetch regs spill (+119MB).
// This removes both causes: fb1->LDS (-24 regs), kbuf gone (-25.6KB LDS),
// independent waves self-pipeline loads.

#define B_N 2048
#define S_N 200
#define D_N 192

typedef __bf16 bf16x8 __attribute__((ext_vector_type(8)));
typedef float  f32x4  __attribute__((ext_vector_type(4)));

__device__ __forceinline__ float rfl(float x) {
  return __uint_as_float(__builtin_amdgcn_readfirstlane(__float_as_uint(x)));
}

struct __align__(16) Smem {
  unsigned char mt[64*400];       // bf16 Mt[h][d]: row stride 400 B, d<192 used
  union {                         // w2t consumed into regs in phase B;
    unsigned char h1w[4][16*144]; // h1w first written in main loop (post-barrier)
    unsigned char w2t[32*144];    // bf16 w2t[k2][h] = W2[h][k2]
  };
  union {                         // qbuf dead after phase B; scores written
    float qbuf[192];              // in main loop
    float scores[256];
  };
  float cbuf[64];
  union {                         // cpart dead after cbuf sum; opart written
    float cpart[4][64];           // after main loop
    float opart[4][192];
  };
  unsigned char maskbuf[256];
  float wm[4], wl[4];             // per-wave softmax state
  float w3buf[32];
  float b2buf[32];
  float consts[4];                // a1, a2, b3
};

__global__ __launch_bounds__(256, 3) void rich_attn_kernel(
    const float* __restrict__ query, const float* __restrict__ keys,
    const int*   __restrict__ keys_mask, const float* __restrict__ W1,
    const float* __restrict__ b1, const float* __restrict__ a1,
    const float* __restrict__ W2, const float* __restrict__ b2,
    const float* __restrict__ a2, const float* __restrict__ W3,
    const float* __restrict__ b3, float* __restrict__ out)
{
  __shared__ Smem sm;
  const int tid  = threadIdx.x;
  const int b    = blockIdx.x;
  const int wave = tid >> 6;
  const int lane = tid & 63;
  const int quad = (tid >> 4) & 3;
  const int n16  = tid & 15;

  // ---- phase A: preload q, mask, scalars, W2^T(bf16), W3 ----
  if (tid < 192) sm.qbuf[tid] = query[b*D_N + tid];
  sm.maskbuf[tid] = (tid < 200) ? (unsigned char)(keys_mask[b*S_N + tid] != 0) : 0;
  if (tid < 32)  sm.w3buf[tid] = W3[tid];
  else if (tid < 64) sm.b2buf[tid-32] = b2[tid-32];
  if (tid == 64) { sm.consts[0] = a1[0]; sm.consts[1] = a2[0]; sm.consts[2] = b3[0]; }
  for (int i = tid; i < 64*32; i += 256) {
    int hh = i >> 5, kk = i & 31;                 // W2[h][k2] row-major
    *((__bf16*)&sm.w2t[kk*144 + hh*2]) = (__bf16)W2[i];
  }
  __syncthreads();

  // ---- phase B: c_b partials; M_b^T -> LDS; fw2 regs ----
  {
    int hh = tid & 63, pp = tid >> 6;
    float acc = 0.f;
    int d0 = pp*48;
    #pragma unroll 4
    for (int d = d0; d < d0+48; ++d)
      acc += sm.qbuf[d] * (W1[(192+d)*64 + hh] - W1[(576+d)*64 + hh]);
    sm.cpart[pp][hh] = acc;
  }
  {
    int h = (wave << 4) | n16;                    // thread covers d = t*32+quad*8+j
    #pragma unroll
    for (int t = 0; t < 6; ++t) {
      bf16x8 fb;
      #pragma unroll
      for (int j = 0; j < 8; ++j) {
        int d = t*32 + quad*8 + j;
        float v = W1[d*64 + h] + W1[(576+d)*64 + h] + sm.qbuf[d]*W1[(384+d)*64 + h];
        fb[j] = (__bf16)v;
      }
      *(bf16x8*)&sm.mt[h*400 + (t*32 + quad*8)*2] = fb;   // Mt[h][d-oct]
      __builtin_amdgcn_sched_barrier(0);          // cap in-flight W1 loads
    }
  }
  bf16x8 fw2[2][2];                               // B-frags for GEMM2, both n-tiles
  #pragma unroll
  for (int nt2 = 0; nt2 < 2; ++nt2)
    #pragma unroll
    for (int t = 0; t < 2; ++t)
      fw2[nt2][t] = *(const bf16x8*)&sm.w2t[(nt2*16 + n16)*144 + (t*32 + quad*8)*2];
  // PER-LANE (n16-indexed) -> VGPRs
  const float w3v0 = sm.w3buf[n16],      w3v1 = sm.w3buf[16 + n16];
  const float bbv0 = sm.b2buf[n16],      bbv1 = sm.b2buf[16 + n16];
  // true scalars -> SGPRs
  const float a1v = rfl(sm.consts[0]), a2v = rfl(sm.consts[1]), b3v = rfl(sm.consts[2]);
  __syncthreads();
  if (tid < 64)
    sm.cbuf[tid] = b1[tid] + sm.cpart[0][tid] + sm.cpart[1][tid]
                 + sm.cpart[2][tid] + sm.cpart[3][tid];
  __syncthreads();                                // cbuf + Mt ready

  // ---- main: wave owns rows [64*wave, 64*wave+64), 4 chunks of 16.
  //      NO barriers from here to the combine. ----
  const float* kb = keys + (size_t)b * (S_N * D_N);
  const int s0 = wave * 64;
  float m_run = -1e30f, l_run = 0.f;
  f32x4 o = {0.f, 0.f, 0.f, 0.f};                 // lanes 0..47 own d = lane*4..+3

  for (int mt = 0; mt < 4; ++mt) {
    const int r0 = s0 + mt*16;

    // A-frags for this 16-row chunk: keys f32 -> bf16, direct from global.
    bf16x8 fa[6];
    {
      int row = r0 + n16;
      bool rv = row < 200;
      const float* kr = kb + (size_t)row * D_N + quad*8;
      #pragma unroll
      for (int t = 0; t < 6; ++t) {
        float4 u0 = make_float4(0.f,0.f,0.f,0.f), u1 = make_float4(0.f,0.f,0.f,0.f);
        if (rv) {
          u0 = *(const float4*)(kr + t*32);
          u1 = *(const float4*)(kr + t*32 + 4);
        }
        fa[t][0]=(__bf16)u0.x; fa[t][1]=(__bf16)u0.y; fa[t][2]=(__bf16)u0.z; fa[t][3]=(__bf16)u0.w;
        fa[t][4]=(__bf16)u1.x; fa[t][5]=(__bf16)u1.y; fa[t][6]=(__bf16)u1.z; fa[t][7]=(__bf16)u1.w;
      }
    }

    // GEMM1: h1_chunk[16 x 64]; nt sequential, acc = 4 regs.
    #pragma unroll
    for (int nt = 0; nt < 4; ++nt) {
      f32x4 acc = (f32x4){0.f,0.f,0.f,0.f};
      #pragma unroll
      for (int t = 0; t < 6; ++t) {
        bf16x8 fb = *(const bf16x8*)&sm.mt[(nt*16 + n16)*400 + (t*32 + quad*8)*2];
        acc = __builtin_amdgcn_mfma_f32_16x16x32_bf16(fa[t], fb, acc, 0, 0, 0);
      }
      float cbv = sm.cbuf[nt*16 + n16];
      #pragma unroll
      for (int r = 0; r < 4; ++r) {               // C: row=quad*4+r, col=n16
        float v = acc[r] + cbv;
        v = (v >= 0.f) ? v : a1v * v;
        *((__bf16*)&sm.h1w[wave][(quad*4 + r)*144 + (nt*16 + n16)*2]) = (__bf16)v;
      }
    }

    // GEMM2: h2_pre[16 x 32] from own h1 chunk (same-wave LDS, no barrier).
    bf16x8 fa2[2];
    #pragma unroll
    for (int t = 0; t < 2; ++t)
      fa2[t] = *(const bf16x8*)&sm.h1w[wave][n16*144 + (t*32 + quad*8)*2];
    f32x4 acc2[2];
    acc2[0] = (f32x4){0.f,0.f,0.f,0.f};
    acc2[1] = (f32x4){0.f,0.f,0.f,0.f};
    #pragma unroll
    for (int nt2 = 0; nt2 < 2; ++nt2)
      #pragma unroll
      for (int t = 0; t < 2; ++t)
        acc2[nt2] = __builtin_amdgcn_mfma_f32_16x16x32_bf16(fa2[t], fw2[nt2][t], acc2[nt2], 0, 0, 0);

    // layer 3: sc[r] for row quad*4+r, butterfly over n16
    float sc[4];
    #pragma unroll
    for (int r = 0; r < 4; ++r) {
      float v0 = acc2[0][r] + bbv0; v0 = (v0 >= 0.f) ? v0 : a2v * v0;
      float v1 = acc2[1][r] + bbv1; v1 = (v1 >= 0.f) ? v1 : a2v * v1;
      sc[r] = v0 * w3v0 + v1 * w3v1;
    }
    #pragma unroll
    for (int off = 1; off < 16; off <<= 1)
      #pragma unroll
      for (int r = 0; r < 4; ++r) sc[r] += __shfl_xor(sc[r], off);

    // mask + online softmax for this 16-row chunk (wave-local)
    float p[4];
    float mloc = -1e30f;
    #pragma unroll
    for (int r = 0; r < 4; ++r) {
      int sg = r0 + quad*4 + r;
      sc[r] += b3v;
      bool valid = (sg < 200) && (sm.maskbuf[sg] != 0);
      sc[r] = valid ? sc[r] : -1e30f;
      mloc = fmaxf(mloc, sc[r]);
    }
    if (n16 == 0) {
      #pragma unroll
      for (int r = 0; r < 4; ++r) sm.scores[r0 + quad*4 + r] = sc[r];
    }
    mloc = fmaxf(mloc, __shfl_xor(mloc, 16));
    mloc = fmaxf(mloc, __shfl_xor(mloc, 32));
    float m_new = fmaxf(m_run, mloc);
    float fac = __expf(m_run - m_new);
    float psum = 0.f;
    #pragma unroll
    for (int r = 0; r < 4; ++r) {
      p[r] = (sc[r] > -1e29f) ? __expf(sc[r] - m_new) : 0.f;
      psum += p[r];
    }
    psum += __shfl_xor(psum, 16);
    psum += __shfl_xor(psum, 32);
    l_run = l_run * fac + psum;
    m_run = m_new;

    // o += p * keys over the chunk's 16 rows; keys re-read from global (L2/L3)
    o[0] *= fac; o[1] *= fac; o[2] *= fac; o[3] *= fac;
    #pragma unroll
    for (int s2 = 0; s2 < 16; ++s2) {
      float pvs = __shfl(p[s2 & 3], (s2 >> 2) * 16);   // all lanes active
      int g = r0 + s2;
      if (lane < 48 && g < 200) {
        float4 kv = *(const float4*)(kb + (size_t)g * D_N + lane*4);
        o[0] += pvs * kv.x;
        o[1] += pvs * kv.y;
        o[2] += pvs * kv.z;
        o[3] += pvs * kv.w;
      }
    }
  }

  // ---- combine 4 per-wave states, finalize ----
  if (lane == 0) { sm.wm[wave] = m_run; sm.wl[wave] = l_run; }
  if (lane < 48) *(f32x4*)&sm.opart[wave][lane*4] = o;
  __syncthreads();
  float mg = fmaxf(fmaxf(sm.wm[0], sm.wm[1]), fmaxf(sm.wm[2], sm.wm[3]));
  float e0 = __expf(sm.wm[0] - mg), e1 = __expf(sm.wm[1] - mg);
  float e2 = __expf(sm.wm[2] - mg), e3 = __expf(sm.wm[3] - mg);
  float lg = sm.wl[0]*e0 + sm.wl[1]*e1 + sm.wl[2]*e2 + sm.wl[3]*e3;
  float invl = (lg > 0.f) ? 1.f / lg : 0.f;
  if (tid < 192) {
    float os = sm.opart[0][tid]*e0 + sm.opart[1][tid]*e1
             + sm.opart[2][tid]*e2 + sm.opart[3][tid]*e3;
    out[(size_t)b * D_N + tid] = os * invl;
  }
  if (tid < 200) {
    float wv = (lg > 0.f) ? __expf(sm.scores[tid] - mg) * invl : 0.f;
    out[(size_t)B_N * D_N + (size_t)b * S_N + tid] = wv;
  }
}

extern "C" void kernel_launch(void* const* d_in, const int* in_sizes, int n_in,
                              void* d_out, int out_size, void* d_ws, size_t ws_size,
                              hipStream_t stream) {
  const float* query     = (const float*)d_in[0];
  const float* keys      = (const float*)d_in[1];
  const int*   keys_mask = (const int*)  d_in[2];
  const float* W1        = (const float*)d_in[3];
  const float* b1        = (const float*)d_in[4];
  const float* a1        = (const float*)d_in[5];
  const float* W2        = (const float*)d_in[6];
  const float* b2        = (const float*)d_in[7];
  const float* a2        = (const float*)d_in[8];
  const float* W3        = (const float*)d_in[9];
  const float* b3        = (const float*)d_in[10];
  float* out = (float*)d_out;
  rich_attn_kernel<<<dim3(B_N), dim3(256), 0, stream>>>(
      query, keys, keys_mask, W1, b1, a1, W2, b2, a2, W3, b3, out);
}